// Round 12
// baseline (293.836 us; speedup 1.0000x reference)
//
#include <hip/hip_runtime.h>
#include <float.h>
#include <math.h>

#define K_CODES 1024
#define ED 64
#define NTOK 131072
#define EPS_DOT 4e-5f   // exact esq bias in score; residual err ~1e-5 + 5e-7 pack

typedef __attribute__((ext_vector_type(8)))  short short8;   // 8 bf16 (4 VGPRs)
typedef __attribute__((ext_vector_type(16))) float float16;  // MFMA 32x32 acc

// ---------------------------------------------------------------------------
// NUMERICS OF THE EXACT PATH ARE FROZEN (rounds 2-11 passed, 0 argmin flips):
//  - zsq / e_sq: numpy pairwise_sum n=64; dot: single sequential fmaf chain;
//  - d2 = fmaf(-2,dot,zsq) + e_sq; argmin smallest index on exact tie.
// Approx: MFMA bf16 hi/lo (hh,hl,lh) + exact fp32 -e_sq/2 via C-init (proven
// r11). NEW (r12): packed-index tracking - low 10 mantissa bits of each score
// replaced by the code id (<=1024 ulp ~ 5e-7 perturbation, folded into EPS);
// per-reg running (P1,P2) via min/max only; one merge per token at the end.
// Top-3-from-pairs is exact unless top-1/2 share a reg slot -> detected by
// (I1&31)==(I2&31) -> full scan. Classification: gap > EPS -> direct; else
// {I1,I2} rescore (res2) unless V3 in band or slot-collision -> full scan.
// Launch count 5 -> 3 (res2+resfull+final fused into vq_cleanup, last-block
// pattern): round-11 evidence shows ~15-20us per-launch overhead.
// ---------------------------------------------------------------------------

static __device__ __forceinline__ unsigned short f2bf(float x) {  // RNE
    unsigned u = __float_as_uint(x);
    u += 0x7fffu + ((u >> 16) & 1u);
    return (unsigned short)(u >> 16);
}
static __device__ __forceinline__ float bf2f(unsigned short h) {
    return __uint_as_float(((unsigned)h) << 16);
}

#define INS3(A1, A2, A3, V) { float _x = fminf(A1, V); A1 = fmaxf(A1, V); \
                              float _y = fminf(A2, _x); A2 = fmaxf(A2, _x); \
                              A3 = fmaxf(A3, _y); }

// ---------------------------------------------------------------------------
// prep: codebook frags (layout proven r6-11) + frozen e_sq; zero counters.
// ---------------------------------------------------------------------------
__global__ __launch_bounds__(256) void vq_prep(const float* __restrict__ cb,
                                               float* __restrict__ e_sq,
                                               short8* __restrict__ efH,
                                               short8* __restrict__ efL,
                                               unsigned int* __restrict__ counts,
                                               float* __restrict__ sse,
                                               unsigned int* __restrict__ wc2,
                                               unsigned int* __restrict__ wcF,
                                               unsigned int* __restrict__ done)
{
#pragma clang fp contract(off)
    const int k = blockIdx.x * 256 + threadIdx.x;   // 0..1023
    const float4* ep = (const float4*)(cb + (size_t)k * ED);
    const int m = k & 31, ct = k >> 5;
    float r[8];
#pragma unroll
    for (int g = 0; g < 8; ++g) {
        float4 a = ep[2 * g], b = ep[2 * g + 1];
        float v[8] = {a.x, a.y, a.z, a.w, b.x, b.y, b.z, b.w};
        short8 hv, lv;
#pragma unroll
        for (int j = 0; j < 8; ++j) {
            unsigned short hb = f2bf(v[j]);
            hv[j] = (short)hb;
            lv[j] = (short)f2bf(v[j] - bf2f(hb));
            const float sq = v[j] * v[j];          // frozen pairwise e_sq
            r[j] = g ? (r[j] + sq) : sq;
        }
        efH[(ct * 8 + g) * 32 + m] = hv;
        efL[(ct * 8 + g) * 32 + m] = lv;
    }
    e_sq[k] = ((r[0] + r[1]) + (r[2] + r[3])) + ((r[4] + r[5]) + (r[6] + r[7]));
    counts[k] = 0u;
    if (k == 0) { *sse = 0.f; *wc2 = 0u; *wcF = 0u; *done = 0u; }
}

// ---------------------------------------------------------------------------
// fused: block = 256 tokens; z->LDS; bf16 hi/lo B-frags in regs; MFMA over 32
// code-tiles, acc C-init = exact -e_sq/2 (LDS, r11-proven); packed-index
// per-reg (P1,P2) tracking; classify at end. LDS ~73.7 KB -> 2 blocks/CU.
// ---------------------------------------------------------------------------
__global__ __launch_bounds__(256, 2) void vq_fused(const float* __restrict__ z_e,
                                                   const float* __restrict__ cb,
                                                   const float* __restrict__ e_sq,
                                                   const short8* __restrict__ efH,
                                                   const short8* __restrict__ efL,
                                                   float* __restrict__ out_zq,
                                                   float* __restrict__ out_idx,
                                                   unsigned int* __restrict__ counts,
                                                   float* __restrict__ sse,
                                                   unsigned int* __restrict__ wl2_tok,
                                                   unsigned int* __restrict__ wl2_idx,
                                                   unsigned int* __restrict__ wc2,
                                                   unsigned int* __restrict__ wlF,
                                                   unsigned int* __restrict__ wcF)
{
#pragma clang fp contract(off)
    __shared__ __align__(16) float zs[256 * 68];       // [token][68]
    __shared__ __align__(16) float bias_l[K_CODES];    // [ct*32 + h*16 + rg]
    __shared__ float wsum[4];

    const int tid = threadIdx.x;
    const int lane = tid & 63, wv = tid >> 6;
    const int ml = lane & 31, h = lane >> 5;
    const int t0 = blockIdx.x * 256;
    const int t  = t0 + tid;                       // this thread's token

    for (int i = tid; i < K_CODES; i += 256) {
        // bias in C/D layout: slot (ct, r5=h*16+rg) -> -e_sq[ct*32+mrow]/2
        const int ct = i >> 5, r5 = i & 31;
        const int hh = r5 >> 4, rg = r5 & 15;
        const int mrow = (rg & 3) + 8 * (rg >> 2) + 4 * hh;
        bias_l[i] = -0.5f * e_sq[ct * 32 + mrow];
    }

    // ---- stage z rows (thread <-> token) ----
    {
        const float4* zp = (const float4*)(z_e + (size_t)t * ED);
#pragma unroll
        for (int j = 0; j < 16; ++j)
            *(float4*)&zs[tid * 68 + 4 * j] = zp[j];
    }
    __syncthreads();

    // ---- convert B-frags (regs): lane (ml,h) -> token wv*64+X*32+ml ----
    short8 zh[2][4], zl[2][4];
#pragma unroll
    for (int X = 0; X < 2; ++X) {
        const int tok = wv * 64 + X * 32 + ml;
#pragma unroll
        for (int q = 0; q < 4; ++q) {
            const int g = q * 2 + h;
            const float* p = &zs[tok * 68 + g * 8];
            float4 a = *(const float4*)p, b = *(const float4*)(p + 4);
            float v[8] = {a.x, a.y, a.z, a.w, b.x, b.y, b.z, b.w};
            short8 hv, lv;
#pragma unroll
            for (int j = 0; j < 8; ++j) {
                unsigned short hb = f2bf(v[j]);
                hv[j] = (short)hb;
                lv[j] = (short)f2bf(v[j] - bf2f(hb));
            }
            zh[X][q] = hv;
            zl[X][q] = lv;
        }
    }

    // ---- per-reg packed running top-2 ----
    float p1[2][16], p2[2][16];
#pragma unroll
    for (int X = 0; X < 2; ++X)
#pragma unroll
        for (int rg = 0; rg < 16; ++rg) { p1[X][rg] = -FLT_MAX; p2[X][rg] = -FLT_MAX; }

    const unsigned h4 = (unsigned)(4 * h);         // per-lane index bits

    short8 ecur[8], enxt[8];                       // [0..3]=H, [4..7]=L
#pragma unroll
    for (int q = 0; q < 4; ++q) {
        const int idx = (q * 2 + h) * 32 + ml;
        ecur[q] = efH[idx]; ecur[4 + q] = efL[idx];
    }

#pragma unroll 2
    for (int ct = 0; ct < 32; ++ct) {
        if (ct < 31) {
#pragma unroll
            for (int q = 0; q < 4; ++q) {
                const int idx = ((ct + 1) * 8 + q * 2 + h) * 32 + ml;
                enxt[q] = efH[idx]; enxt[4 + q] = efL[idx];
            }
        }
        // acc C-init = exact -e_sq/2 (r11-proven)
        const float4* bp = (const float4*)&bias_l[ct * 32 + h * 16];
        const float4 b0 = bp[0], b1 = bp[1], b2 = bp[2], b3 = bp[3];
        float16 acc0;
        acc0[0] = b0.x; acc0[1] = b0.y; acc0[2]  = b0.z; acc0[3]  = b0.w;
        acc0[4] = b1.x; acc0[5] = b1.y; acc0[6]  = b1.z; acc0[7]  = b1.w;
        acc0[8] = b2.x; acc0[9] = b2.y; acc0[10] = b2.z; acc0[11] = b2.w;
        acc0[12] = b3.x; acc0[13] = b3.y; acc0[14] = b3.z; acc0[15] = b3.w;
        float16 acc1 = acc0;
#pragma unroll
        for (int q = 0; q < 4; ++q) {              // proven order: hh, hl, lh
            acc0 = __builtin_amdgcn_mfma_f32_32x32x16_bf16(ecur[q],     zh[0][q], acc0, 0, 0, 0);
            acc1 = __builtin_amdgcn_mfma_f32_32x32x16_bf16(ecur[q],     zh[1][q], acc1, 0, 0, 0);
            acc0 = __builtin_amdgcn_mfma_f32_32x32x16_bf16(ecur[q],     zl[0][q], acc0, 0, 0, 0);
            acc1 = __builtin_amdgcn_mfma_f32_32x32x16_bf16(ecur[q],     zl[1][q], acc1, 0, 0, 0);
            acc0 = __builtin_amdgcn_mfma_f32_32x32x16_bf16(ecur[4 + q], zh[0][q], acc0, 0, 0, 0);
            acc1 = __builtin_amdgcn_mfma_f32_32x32x16_bf16(ecur[4 + q], zh[1][q], acc1, 0, 0, 0);
        }
        // packed tracking: 5 VALU/reg, no branches, no shfl
#pragma unroll
        for (int X = 0; X < 2; ++X) {
            const float16 acc = X ? acc1 : acc0;
#pragma unroll
            for (int rg = 0; rg < 16; ++rg) {
                const unsigned scode = (unsigned)(ct * 32 + (rg & 3) + 8 * (rg >> 2)); // uniform
                const unsigned ub = ((__float_as_uint(acc[rg]) & 0xFFFFFC00u) | scode) | h4;
                const float pv = __uint_as_float(ub);
                p2[X][rg] = fmaxf(p2[X][rg], fminf(p1[X][rg], pv));
                p1[X][rg] = fmaxf(p1[X][rg], pv);
            }
        }
#pragma unroll
        for (int i = 0; i < 8; ++i) ecur[i] = enxt[i];
    }

    // ---- final per-token merge (once): keep X=h, send X=1-h ----
    float k1 = -FLT_MAX, k2 = -FLT_MAX, k3 = -FLT_MAX;
    float s1 = -FLT_MAX, s2 = -FLT_MAX, s3 = -FLT_MAX;
#pragma unroll
    for (int rg = 0; rg < 16; ++rg) {
        const float q1 = h ? p1[1][rg] : p1[0][rg];
        const float q2 = h ? p2[1][rg] : p2[0][rg];
        const float r1 = h ? p1[0][rg] : p1[1][rg];
        const float r2 = h ? p2[0][rg] : p2[1][rg];
        INS3(k1, k2, k3, q1); INS3(k1, k2, k3, q2);
        INS3(s1, s2, s3, r1); INS3(s1, s2, s3, r2);
    }
    {
        const float g1 = __shfl_xor(s1, 32);
        const float g2 = __shfl_xor(s2, 32);
        const float g3 = __shfl_xor(s3, 32);
        INS3(k1, k2, k3, g1); INS3(k1, k2, k3, g2); INS3(k1, k2, k3, g3);
    }

    const int I1 = (int)(__float_as_uint(k1) & 1023u);
    const int I2 = (int)(__float_as_uint(k2) & 1023u);
    const bool amb = (k2 >= k1 - EPS_DOT);

    float lsse = 0.f;
    if (!amb) {
        const int bi = I1;                         // provably exact argmin
        atomicAdd(&counts[bi], 1u);
        out_idx[t] = (float)bi;
        const float4* eq = (const float4*)(cb + (size_t)bi * ED);
        float4* oz = (float4*)(out_zq + (size_t)t * ED);
#pragma unroll
        for (int i = 0; i < 16; ++i) {
            float4 q = eq[i];
            oz[i] = q;
            const float* zrow = &zs[tid * 68 + 4 * i];
            float dx = q.x - zrow[0]; lsse = fmaf(dx, dx, lsse);
            float dy = q.y - zrow[1]; lsse = fmaf(dy, dy, lsse);
            float dz = q.z - zrow[2]; lsse = fmaf(dz, dz, lsse);
            float dw = q.w - zrow[3]; lsse = fmaf(dw, dw, lsse);
        }
    } else if (k3 < k1 - EPS_DOT && ((I1 & 31) != (I2 & 31))) {
        // exact argmin in {I1,I2} (top-3-from-pairs valid: no slot collision)
        const unsigned pos = atomicAdd(wc2, 1u);
        wl2_tok[pos] = (unsigned)t;
        wl2_idx[pos] = (unsigned)I1 | ((unsigned)I2 << 16);
    } else {
        const unsigned pos = atomicAdd(wcF, 1u);   // rare: full scan
        wlF[pos] = (unsigned)t;
    }

    // block SSE reduce (unambiguous tokens only)
#pragma unroll
    for (int off = 32; off > 0; off >>= 1)
        lsse += __shfl_down(lsse, off, 64);
    if (lane == 0) wsum[wv] = lsse;
    __syncthreads();
    if (tid == 0)
        atomicAdd(sse, (wsum[0] + wsum[1]) + (wsum[2] + wsum[3]));
}

// ---------------------------------------------------------------------------
// cleanup: res2 (thread/token, frozen 2-candidate rescore) + resfull (wave/
// token, frozen full scan) + last-block final scalars. All streamed loads,
// ~10 live scalars (r8/9/10 spill lessons).
// ---------------------------------------------------------------------------
__global__ __launch_bounds__(256) void vq_cleanup(const float* __restrict__ z_e,
                                                  const float* __restrict__ cb,
                                                  const float* __restrict__ e_sq,
                                                  const unsigned int* __restrict__ wl2_tok,
                                                  const unsigned int* __restrict__ wl2_idx,
                                                  const unsigned int* __restrict__ wc2,
                                                  const unsigned int* __restrict__ wlF,
                                                  const unsigned int* __restrict__ wcF,
                                                  float* __restrict__ out_zq,
                                                  float* __restrict__ out_idx,
                                                  unsigned int* __restrict__ counts,
                                                  float* __restrict__ sse,
                                                  unsigned int* __restrict__ done,
                                                  float* __restrict__ out_sc)
{
#pragma clang fp contract(off)
    const int tid = threadIdx.x, lane = tid & 63, wv = tid >> 6;
    const int gtid = blockIdx.x * 256 + tid;
    const int nth = gridDim.x * 256;

    // ---- part A: 2-candidate rescore ----
    const int n2 = (int)*wc2;
    float lsse = 0.f;
    for (int i = gtid; i < n2; i += nth) {
        const int t = (int)wl2_tok[i];
        const unsigned pk = wl2_idx[i];
        const int c1 = (int)(pk & 0xFFFFu), c2 = (int)(pk >> 16);
        const float4* zp = (const float4*)(z_e + (size_t)t * ED);

        float r[8];
#pragma unroll
        for (int g = 0; g < 8; ++g) {              // frozen pairwise zsq
            const float4 a = zp[2 * g], b = zp[2 * g + 1];
            if (g == 0) {
                r[0] = a.x * a.x; r[1] = a.y * a.y; r[2] = a.z * a.z; r[3] = a.w * a.w;
                r[4] = b.x * b.x; r[5] = b.y * b.y; r[6] = b.z * b.z; r[7] = b.w * b.w;
            } else {
                r[0] = r[0] + a.x * a.x; r[1] = r[1] + a.y * a.y;
                r[2] = r[2] + a.z * a.z; r[3] = r[3] + a.w * a.w;
                r[4] = r[4] + b.x * b.x; r[5] = r[5] + b.y * b.y;
                r[6] = r[6] + b.z * b.z; r[7] = r[7] + b.w * b.w;
            }
        }
        const float zsq =
            ((r[0] + r[1]) + (r[2] + r[3])) + ((r[4] + r[5]) + (r[6] + r[7]));

        float d2v[2];
        const int cc[2] = {c1, c2};
#pragma unroll
        for (int s = 0; s < 2; ++s) {
            const float4* e4 = (const float4*)(cb + (size_t)cc[s] * ED);
            float a = 0.f;
#pragma unroll 4
            for (int j = 0; j < 16; ++j) {         // streamed, frozen chain
                const float4 zv = zp[j];
                const float4 ev = e4[j];
                a = fmaf(zv.x, ev.x, a);
                a = fmaf(zv.y, ev.y, a);
                a = fmaf(zv.z, ev.z, a);
                a = fmaf(zv.w, ev.w, a);
            }
            d2v[s] = fmaf(-2.f, a, zsq) + e_sq[cc[s]];
        }
        int bi = c1;
        if (d2v[1] < d2v[0] || (d2v[1] == d2v[0] && c2 < c1)) bi = c2;

        out_idx[t] = (float)bi;
        atomicAdd(&counts[bi], 1u);
        const float4* eq = (const float4*)(cb + (size_t)bi * ED);
        float4* oz = (float4*)(out_zq + (size_t)t * ED);
#pragma unroll
        for (int j = 0; j < 16; ++j) {
            const float4 q = eq[j];
            const float4 zv = zp[j];
            oz[j] = q;
            float dx = q.x - zv.x; lsse = fmaf(dx, dx, lsse);
            float dy = q.y - zv.y; lsse = fmaf(dy, dy, lsse);
            float dz = q.z - zv.z; lsse = fmaf(dz, dz, lsse);
            float dw = q.w - zv.w; lsse = fmaf(dw, dw, lsse);
        }
    }
#pragma unroll
    for (int off = 32; off > 0; off >>= 1)
        lsse += __shfl_down(lsse, off, 64);
    if (lane == 0 && lsse != 0.f) atomicAdd(sse, lsse);

    // ---- part B: full scan (one wave per token) ----
    const int nF = (int)*wcF;
    const int wave = blockIdx.x * 4 + wv, nw = gridDim.x * 4;
    for (int it = wave; it < nF; it += nw) {
        const int t = (int)wlF[it];
        const float4* zp = (const float4*)(z_e + (size_t)t * ED);

        float r[8];
#pragma unroll
        for (int g = 0; g < 8; ++g) {
            const float4 a = zp[2 * g], b = zp[2 * g + 1];
            if (g == 0) {
                r[0] = a.x * a.x; r[1] = a.y * a.y; r[2] = a.z * a.z; r[3] = a.w * a.w;
                r[4] = b.x * b.x; r[5] = b.y * b.y; r[6] = b.z * b.z; r[7] = b.w * b.w;
            } else {
                r[0] = r[0] + a.x * a.x; r[1] = r[1] + a.y * a.y;
                r[2] = r[2] + a.z * a.z; r[3] = r[3] + a.w * a.w;
                r[4] = r[4] + b.x * b.x; r[5] = r[5] + b.y * b.y;
                r[6] = r[6] + b.z * b.z; r[7] = r[7] + b.w * b.w;
            }
        }
        const float zsq =
            ((r[0] + r[1]) + (r[2] + r[3])) + ((r[4] + r[5]) + (r[6] + r[7]));

        float best = FLT_MAX;
        int bi = K_CODES;
        for (int cc = 0; cc < 16; ++cc) {
            const int c = cc * 64 + lane;
            const float4* e4 = (const float4*)(cb + (size_t)c * ED);
            float a = 0.f;
#pragma unroll 4
            for (int j = 0; j < 16; ++j) {
                const float4 zv = zp[j];
                const float4 ev = e4[j];
                a = fmaf(zv.x, ev.x, a);
                a = fmaf(zv.y, ev.y, a);
                a = fmaf(zv.z, ev.z, a);
                a = fmaf(zv.w, ev.w, a);
            }
            const float d2 = fmaf(-2.f, a, zsq) + e_sq[c];
            if (d2 < best || (d2 == best && c < bi)) { best = d2; bi = c; }
        }
#pragma unroll
        for (int off = 32; off > 0; off >>= 1) {
            const float ov = __shfl_xor(best, off);
            const int   oi = __shfl_xor(bi, off);
            if (ov < best || (ov == best && oi < bi)) { best = ov; bi = oi; }
        }
        const float qd = cb[(size_t)bi * ED + lane];
        const float zd = z_e[(size_t)t * ED + lane];
        out_zq[(size_t)t * ED + lane] = qd;
        float s = (qd - zd) * (qd - zd);
#pragma unroll
        for (int off = 32; off > 0; off >>= 1)
            s += __shfl_down(s, off, 64);
        if (lane == 0) {
            atomicAdd(sse, s);
            atomicAdd(&counts[bi], 1u);
            out_idx[t] = (float)bi;
        }
    }

    // ---- part C: last block computes the loss scalars ----
    __syncthreads();
    __threadfence();
    __shared__ unsigned lastf;
    if (tid == 0)
        lastf = (atomicAdd(done, 1u) == (unsigned)(gridDim.x - 1)) ? 1u : 0u;
    __syncthreads();
    if (lastf) {
        __shared__ float red[256];
        float acc = 0.f;
        for (int i = tid; i < K_CODES; i += 256) {
            const unsigned c = atomicAdd(&counts[i], 0u);     // coherent read
            const float p = (float)c / (float)NTOK + 1e-10f;
            acc = acc + p * logf(p);
        }
        red[tid] = acc;
        __syncthreads();
        for (int s = 128; s > 0; s >>= 1) {
            if (tid < s) red[tid] += red[tid + s];
            __syncthreads();
        }
        if (tid == 0) {
            const float entropy = -red[0];
            const float sv = atomicAdd(sse, 0.f);              // coherent read
            const float cbl = sv / ((float)NTOK * (float)ED);
            out_sc[0] = cbl;                                   // codebook_loss
            out_sc[1] = 0.25f * cbl;                           // commitment_loss
            out_sc[2] = -0.1f * (entropy / 6.93147180559945f); // entropy_loss
            out_sc[3] = expf(entropy);                         // perplexity
        }
    }
}

// ---------------------------------------------------------------------------
extern "C" void kernel_launch(void* const* d_in, const int* in_sizes, int n_in,
                              void* d_out, int out_size, void* d_ws, size_t ws_size,
                              hipStream_t stream)
{
    const float* z_e = (const float*)d_in[0];
    const float* cb  = (const float*)d_in[1];

    float* out   = (float*)d_out;
    float* o_zq  = out;                              // [131072,64]
    float* o_idx = out + (size_t)NTOK * ED;          // [131072] (as float)
    float* o_sc  = o_idx + NTOK;                     // 4 scalars

    char* ws = (char*)d_ws;
    float*        e_sq    = (float*)(ws);                    // 4 KB
    unsigned int* counts  = (unsigned int*)(ws + 4096);      // 4 KB
    float*        sse     = (float*)(ws + 8192);             // 4 B
    unsigned int* wc2     = (unsigned int*)(ws + 8196);      // 4 B
    unsigned int* wcF     = (unsigned int*)(ws + 8200);      // 4 B
    unsigned int* done    = (unsigned int*)(ws + 8204);      // 4 B
    unsigned int* wl2_tok = (unsigned int*)(ws + 12288);     // 512 KB
    unsigned int* wl2_idx = (unsigned int*)(ws + 536576);    // 512 KB
    unsigned int* wlF     = (unsigned int*)(ws + 1060864);   // 512 KB
    short8*       efH     = (short8*)(ws + 1585152);         // 128 KB
    short8*       efL     = (short8*)(ws + 1716224);         // 128 KB

    vq_prep   <<<4, 256, 0, stream>>>(cb, e_sq, efH, efL, counts, sse,
                                      wc2, wcF, done);
    vq_fused  <<<NTOK / 256, 256, 0, stream>>>(z_e, cb, e_sq, efH, efL,
                                               o_zq, o_idx, counts, sse,
                                               wl2_tok, wl2_idx, wc2, wlF, wcF);
    vq_cleanup<<<256, 256, 0, stream>>>(z_e, cb, e_sq, wl2_tok, wl2_idx, wc2,
                                        wlF, wcF, o_zq, o_idx, counts, sse,
                                        done, o_sc);
}